// Round 10
// baseline (315.185 us; speedup 1.0000x reference)
//
#include <hip/hip_runtime.h>
#include <hip/hip_bf16.h>

#define VOCAB 256
#define EMB   32
#define HID   128
#define GATES 512
#define BATCH 512
#define SEQ   512
#define HSTRIDE 144   // shorts; 288 B row stride -> uniform 2-way LDS access (free)

#define LOG2E 1.442695041f
#if __has_builtin(__builtin_amdgcn_exp2f)
#define GEXP(x) __builtin_amdgcn_exp2f(x)
#define SCALE_IFO LOG2E
#define SCALE_G   (2.0f * LOG2E)
#else
#define GEXP(x) __expf(x)
#define SCALE_IFO 1.0f
#define SCALE_G   2.0f
#endif

typedef __attribute__((ext_vector_type(8))) short bf16x8;
typedef __attribute__((ext_vector_type(4))) float f32x4;

static __device__ __forceinline__ unsigned short f2bf(float f) {
  unsigned int u = __float_as_uint(f);
  return (unsigned short)((u + 0x7fffu + ((u >> 16) & 1u)) >> 16);
}

// ws layout: P[VOCAB][GATES] f32 (512 KB), PRESCALED per gate type
// (i,f,o by SCALE_IFO; g by SCALE_G) so gate math uses raw 2^x.
__global__ __launch_bounds__(256) void prep_kernel(
    const float* __restrict__ emb, const float* __restrict__ W_ih,
    const float* __restrict__ b_ih, const float* __restrict__ b_hh,
    float* __restrict__ P) {
  const int wg  = blockIdx.x;
  const int tid = threadIdx.x;
  __shared__ float e[EMB];
  if (tid < EMB) e[tid] = emb[wg * EMB + tid];
  __syncthreads();
  for (int g = tid; g < GATES; g += 256) {
    float acc = b_ih[g] + b_hh[g];
    const float* w = W_ih + g * EMB;
    #pragma unroll
    for (int k = 0; k < EMB; ++k) acc += e[k] * w[k];
    const float sc = ((g >> 7) == 2) ? SCALE_G : SCALE_IFO;
    P[wg * GATES + g] = acc * sc;
  }
}

// 128 WGs x 512 threads (8 waves = 2/SIMD). WG owns batch rows b0..b0+3.
// wave w owns j in [16w,16w+16) for all 4 gate types (4 n-tiles x 4 ks).
// A row m = h[m&3] => acc reg r = batch row r for every lane.
// Lane (c16,kg) owns output (row=kg, j=16w+c16)  [bijective, 512 lanes].
// Chain surgery vs r9: A-frag ds_reads issue FIRST after the barrier (the
// chars/P prefetch used to queue ahead of them in the in-order LDS return
// stream, putting ~120 cyc on the h critical path); P prefetch alternates
// between two register sets across the x2 unroll (no p=q copies, vmcnt
// dependency moves to next step's gate math).
__global__ __launch_bounds__(512, 2) void lstm_kernel(
    const int* __restrict__ inputs, const float* __restrict__ P,
    const float* __restrict__ W_hh,
    const float* __restrict__ W_cls, const float* __restrict__ b_cls,
    float* __restrict__ out) {
  const int wg   = blockIdx.x;
  const int tid  = threadIdx.x;
  const int wave = tid >> 6;          // 0..7
  const int lane = tid & 63;
  const int c16  = lane & 15;
  const int kg   = lane >> 4;         // 0..3
  const int b0   = wg * 4;

  const int row   = kg;                        // this lane's batch row (0..3)
  const int jfull = wave * 16 + c16;           // 0..127 hidden index

  __shared__ unsigned char  chars[4][SEQ];        // 2 KB
  __shared__ unsigned short hbufA[4 * HSTRIDE];   // even steps read A, write B
  __shared__ unsigned short hbufB[4 * HSTRIDE];
  __shared__ float          h_last[4][HID];       // 2 KB

  for (int k = tid; k < 4 * SEQ; k += 512) {
    const int r = k >> 9, t = k & (SEQ - 1);
    chars[r][t] = (unsigned char)(inputs[(b0 + r) * SEQ + t] & 0xff);
  }
  for (int k = tid; k < 4 * HSTRIDE; k += 512) { hbufA[k] = 0; hbufB[k] = 0; }

  // B-frags: convert W_hh f32 -> prescaled bf16 in-register (one-time; L2-served)
  // Bfrag[gt][ks] lane (c16,kg) = W_hh[gt*128+16w+c16][ks*32+kg*8..+7] * scale(gt)
  bf16x8 Bfrag[4][4];
  #pragma unroll
  for (int gt = 0; gt < 4; ++gt) {
    const float sc = (gt == 2) ? SCALE_G : SCALE_IFO;
    const float* wr = W_hh + (gt * 128 + wave * 16 + c16) * HID + kg * 8;
    #pragma unroll
    for (int ks = 0; ks < 4; ++ks) {
      const float4 w0 = *(const float4*)(wr + ks * 32);
      const float4 w1 = *(const float4*)(wr + ks * 32 + 4);
      bf16x8 b;
      b[0] = (short)f2bf(w0.x * sc); b[1] = (short)f2bf(w0.y * sc);
      b[2] = (short)f2bf(w0.z * sc); b[3] = (short)f2bf(w0.w * sc);
      b[4] = (short)f2bf(w1.x * sc); b[5] = (short)f2bf(w1.y * sc);
      b[6] = (short)f2bf(w1.z * sc); b[7] = (short)f2bf(w1.w * sc);
      Bfrag[gt][ks] = b;
    }
  }

  const int aoff = (c16 & 3) * HSTRIDE + kg * 8;   // A-frag: h[c16&3][kg*8..]
  const float* Pj = P + jfull;
  float cstate = 0.f;
  float hv = 0.f;

  __syncthreads();

  // step-0 P values into the p-set; q-set filled by STEP 0's prefetch
  float p0, p1, p2, p3, q0, q1, q2, q3;
  {
    const float* Pr0 = Pj + ((size_t)chars[row][0] << 9);
    p0 = Pr0[0]; p1 = Pr0[128]; p2 = Pr0[256]; p3 = Pr0[384];
  }

#define STEP(HIN, HOUT, T, PA0, PA1, PA2, PA3, PB0, PB1, PB2, PB3)             \
  {                                                                            \
    /* A-frag ds_reads FIRST: they gate the MFMA chain */                      \
    const unsigned short* hb = (HIN) + aoff;                                   \
    const bf16x8 A0 = *(const bf16x8*)(hb);                                    \
    const bf16x8 A1 = *(const bf16x8*)(hb + 32);                               \
    const bf16x8 A2 = *(const bf16x8*)(hb + 64);                               \
    const bf16x8 A3 = *(const bf16x8*)(hb + 96);                               \
    /* next step's P prefetch: issues behind A-reads, lands during MFMAs */    \
    {                                                                          \
      const int chn = chars[row][((T) + 1) & (SEQ - 1)];                       \
      const float* Pn = Pj + ((size_t)chn << 9);                               \
      PB0 = Pn[0]; PB1 = Pn[128]; PB2 = Pn[256]; PB3 = Pn[384];                \
    }                                                                          \
    f32x4 a0 = {}, a1 = {}, a2 = {}, a3 = {};                                  \
    a0 = __builtin_amdgcn_mfma_f32_16x16x32_bf16(A0, Bfrag[0][0], a0, 0,0,0);  \
    a1 = __builtin_amdgcn_mfma_f32_16x16x32_bf16(A0, Bfrag[1][0], a1, 0,0,0);  \
    a2 = __builtin_amdgcn_mfma_f32_16x16x32_bf16(A0, Bfrag[2][0], a2, 0,0,0);  \
    a3 = __builtin_amdgcn_mfma_f32_16x16x32_bf16(A0, Bfrag[3][0], a3, 0,0,0);  \
    a0 = __builtin_amdgcn_mfma_f32_16x16x32_bf16(A1, Bfrag[0][1], a0, 0,0,0);  \
    a1 = __builtin_amdgcn_mfma_f32_16x16x32_bf16(A1, Bfrag[1][1], a1, 0,0,0);  \
    a2 = __builtin_amdgcn_mfma_f32_16x16x32_bf16(A1, Bfrag[2][1], a2, 0,0,0);  \
    a3 = __builtin_amdgcn_mfma_f32_16x16x32_bf16(A1, Bfrag[3][1], a3, 0,0,0);  \
    a0 = __builtin_amdgcn_mfma_f32_16x16x32_bf16(A2, Bfrag[0][2], a0, 0,0,0);  \
    a1 = __builtin_amdgcn_mfma_f32_16x16x32_bf16(A2, Bfrag[1][2], a1, 0,0,0);  \
    a2 = __builtin_amdgcn_mfma_f32_16x16x32_bf16(A2, Bfrag[2][2], a2, 0,0,0);  \
    a3 = __builtin_amdgcn_mfma_f32_16x16x32_bf16(A2, Bfrag[3][2], a3, 0,0,0);  \
    a0 = __builtin_amdgcn_mfma_f32_16x16x32_bf16(A3, Bfrag[0][3], a0, 0,0,0);  \
    a1 = __builtin_amdgcn_mfma_f32_16x16x32_bf16(A3, Bfrag[1][3], a1, 0,0,0);  \
    a2 = __builtin_amdgcn_mfma_f32_16x16x32_bf16(A3, Bfrag[2][3], a2, 0,0,0);  \
    a3 = __builtin_amdgcn_mfma_f32_16x16x32_bf16(A3, Bfrag[3][3], a3, 0,0,0);  \
    const float gi = (kg & 2) ? ((kg & 1) ? a0[3] : a0[2])                     \
                              : ((kg & 1) ? a0[1] : a0[0]);                    \
    const float gf = (kg & 2) ? ((kg & 1) ? a1[3] : a1[2])                     \
                              : ((kg & 1) ? a1[1] : a1[0]);                    \
    const float gg = (kg & 2) ? ((kg & 1) ? a2[3] : a2[2])                     \
                              : ((kg & 1) ? a2[1] : a2[0]);                    \
    const float go = (kg & 2) ? ((kg & 1) ? a3[3] : a3[2])                     \
                              : ((kg & 1) ? a3[1] : a3[0]);                    \
    const float iv = __builtin_amdgcn_rcpf(1.f + GEXP(-(gi + PA0)));           \
    const float fv = __builtin_amdgcn_rcpf(1.f + GEXP(-(gf + PA1)));           \
    const float gv = 1.f - 2.f * __builtin_amdgcn_rcpf(GEXP(gg + PA2) + 1.f);  \
    const float ov = __builtin_amdgcn_rcpf(1.f + GEXP(-(go + PA3)));           \
    cstate = fv * cstate + iv * gv;                                            \
    const float th =                                                           \
        1.f - 2.f * __builtin_amdgcn_rcpf(GEXP(cstate * SCALE_G) + 1.f);       \
    hv = ov * th;                                                              \
    (HOUT)[row * HSTRIDE + jfull] = f2bf(hv);                                  \
    __syncthreads();                                                           \
  }

  #pragma unroll 1
  for (int t = 0; t < SEQ; t += 2) {
    STEP(hbufA, hbufB, t,     p0, p1, p2, p3, q0, q1, q2, q3)
    STEP(hbufB, hbufA, t + 1, q0, q1, q2, q3, p0, p1, p2, p3)
  }
#undef STEP

  // final h written once
  h_last[row][jfull] = hv;
  __syncthreads();

  // classifier: 4 rows x 256 vocab = 1024 outputs, 2 per thread
  const int erow = tid >> 7;          // 0..3
  const int ej   = tid & 127;
  #pragma unroll
  for (int half = 0; half < 2; ++half) {
    const int v = ej + half * 128;
    float acc = b_cls[v];
    const float4* w  = (const float4*)(W_cls + v * HID);
    const float4* hh = (const float4*)&h_last[erow][0];
    #pragma unroll
    for (int k = 0; k < HID / 4; ++k) {
      const float4 wv = w[k];
      const float4 hv4 = hh[k];
      acc += wv.x * hv4.x + wv.y * hv4.y + wv.z * hv4.z + wv.w * hv4.w;
    }
    out[(b0 + erow) * VOCAB + v] = acc;
  }
}

extern "C" void kernel_launch(void* const* d_in, const int* in_sizes, int n_in,
                              void* d_out, int out_size, void* d_ws, size_t ws_size,
                              hipStream_t stream) {
  const int*   inputs = (const int*)d_in[0];
  const float* emb    = (const float*)d_in[1];
  const float* W_ih   = (const float*)d_in[2];
  const float* W_hh   = (const float*)d_in[3];
  const float* b_ih   = (const float*)d_in[4];
  const float* b_hh   = (const float*)d_in[5];
  const float* W_cls  = (const float*)d_in[6];
  const float* b_cls  = (const float*)d_in[7];
  float* outp = (float*)d_out;

  float* Ptab = (float*)d_ws;

  prep_kernel<<<VOCAB, 256, 0, stream>>>(emb, W_ih, b_ih, b_hh, Ptab);
  lstm_kernel<<<BATCH / 4, 512, 0, stream>>>(inputs, Ptab, W_hh, W_cls, b_cls, outp);
}

// Round 11
// 309.839 us; speedup vs baseline: 1.0173x; 1.0173x over previous
//
#include <hip/hip_runtime.h>
#include <hip/hip_bf16.h>

#define VOCAB 256
#define EMB   32
#define HID   128
#define GATES 512
#define BATCH 512
#define SEQ   512
#define HSTRIDE 144   // shorts; 288 B row stride -> uniform 2-way LDS access (free)

#define LOG2E 1.442695041f
#if __has_builtin(__builtin_amdgcn_exp2f)
#define GEXP(x) __builtin_amdgcn_exp2f(x)
#define SCALE_IFO LOG2E
#define SCALE_G   (2.0f * LOG2E)
#else
#define GEXP(x) __expf(x)
#define SCALE_IFO 1.0f
#define SCALE_G   2.0f
#endif

// h-writes drained (lgkm), P global loads stay in flight across the barrier
#define FAST_BARRIER() asm volatile("s_waitcnt lgkmcnt(0)\n\ts_barrier" ::: "memory")

typedef __attribute__((ext_vector_type(8))) short bf16x8;
typedef __attribute__((ext_vector_type(4))) float f32x4;

static __device__ __forceinline__ unsigned short f2bf(float f) {
  unsigned int u = __float_as_uint(f);
  return (unsigned short)((u + 0x7fffu + ((u >> 16) & 1u)) >> 16);
}

// ws layout: P[VOCAB][GATES] f32 (512 KB), PRESCALED per gate type
// (i,f,o by SCALE_IFO; g by SCALE_G) so gate math uses raw 2^x.
__global__ __launch_bounds__(256) void prep_kernel(
    const float* __restrict__ emb, const float* __restrict__ W_ih,
    const float* __restrict__ b_ih, const float* __restrict__ b_hh,
    float* __restrict__ P) {
  const int wg  = blockIdx.x;
  const int tid = threadIdx.x;
  __shared__ float e[EMB];
  if (tid < EMB) e[tid] = emb[wg * EMB + tid];
  __syncthreads();
  for (int g = tid; g < GATES; g += 256) {
    float acc = b_ih[g] + b_hh[g];
    const float* w = W_ih + g * EMB;
    #pragma unroll
    for (int k = 0; k < EMB; ++k) acc += e[k] * w[k];
    const float sc = ((g >> 7) == 2) ? SCALE_G : SCALE_IFO;
    P[wg * GATES + g] = acc * sc;
  }
}

// 128 WGs x 512 threads (8 waves = 2/SIMD). WG owns batch rows b0..b0+3.
// wave w owns j in [16w,16w+16) for all 4 gate types (4 n-tiles x 4 ks).
// A row m = h[m>>2] (4x replication) => lane (c16,kg)'s gate for its
// (row=kg, j=16w+c16) lands in REG 0 of every acc (D row 4kg, col c16):
// no cndmask selects. One lean barrier/step (lgkm-only drain); per-step P
// address from an offs[] LDS byte-offset table (1 broadcast ds_read_b32);
// h -> bf16 via single v_cvt_pk_bf16_f32.
__global__ __launch_bounds__(512, 2) void lstm_kernel(
    const int* __restrict__ inputs, const float* __restrict__ P,
    const float* __restrict__ W_hh,
    const float* __restrict__ W_cls, const float* __restrict__ b_cls,
    float* __restrict__ out) {
  const int wg   = blockIdx.x;
  const int tid  = threadIdx.x;
  const int wave = tid >> 6;          // 0..7
  const int lane = tid & 63;
  const int c16  = lane & 15;
  const int kg   = lane >> 4;         // 0..3
  const int b0   = wg * 4;

  const int row   = kg;                        // this lane's batch row (0..3)
  const int jfull = wave * 16 + c16;           // 0..127 hidden index

  __shared__ unsigned int   offs[SEQ][4];         // 8 KB: P byte offsets (ch*2048)
  __shared__ unsigned short hbufA[4 * HSTRIDE];   // even steps read A, write B
  __shared__ unsigned short hbufB[4 * HSTRIDE];
  __shared__ float          h_last[4][HID];       // 2 KB

  for (int k = tid; k < 4 * SEQ; k += 512) {
    const int r = k & 3, t = k >> 2;
    offs[t][r] = ((unsigned int)(inputs[(b0 + r) * SEQ + t] & 0xff)) << 11;
  }
  for (int k = tid; k < 4 * HSTRIDE; k += 512) { hbufA[k] = 0; hbufB[k] = 0; }

  // B-frags: convert W_hh f32 -> prescaled bf16 in-register (one-time; L2-served)
  // Bfrag[gt][ks] lane (c16,kg) = W_hh[gt*128+16w+c16][ks*32+kg*8..+7] * scale(gt)
  bf16x8 Bfrag[4][4];
  #pragma unroll
  for (int gt = 0; gt < 4; ++gt) {
    const float sc = (gt == 2) ? SCALE_G : SCALE_IFO;
    const float* wr = W_hh + (gt * 128 + wave * 16 + c16) * HID + kg * 8;
    #pragma unroll
    for (int ks = 0; ks < 4; ++ks) {
      const float4 w0 = *(const float4*)(wr + ks * 32);
      const float4 w1 = *(const float4*)(wr + ks * 32 + 4);
      bf16x8 b;
      b[0] = (short)f2bf(w0.x * sc); b[1] = (short)f2bf(w0.y * sc);
      b[2] = (short)f2bf(w0.z * sc); b[3] = (short)f2bf(w0.w * sc);
      b[4] = (short)f2bf(w1.x * sc); b[5] = (short)f2bf(w1.y * sc);
      b[6] = (short)f2bf(w1.z * sc); b[7] = (short)f2bf(w1.w * sc);
      Bfrag[gt][ks] = b;
    }
  }

  // A-frag: lane (c16,kg) reads h[c16>>2][kg*8 .. +7] (+ks*32)
  //   -> A row m = h[m>>2]; uniform 2-way banks + 4-way broadcast (free)
  const int aoff = (c16 >> 2) * HSTRIDE + kg * 8;
  const char* PjB = (const char*)(P + jfull);
  float cstate = 0.f;
  float hv = 0.f;

  __syncthreads();

  // step-0 P values into the p-set; q-set filled by STEP 0's prefetch
  float p0, p1, p2, p3, q0, q1, q2, q3;
  {
    const float* Pr0 = (const float*)(PjB + offs[0][row]);
    p0 = Pr0[0]; p1 = Pr0[128]; p2 = Pr0[256]; p3 = Pr0[384];
  }

#define STEP(HIN, HOUT, T, PA0, PA1, PA2, PA3, PB0, PB1, PB2, PB3)             \
  {                                                                            \
    /* A-frag ds_reads FIRST: they gate the MFMA chain */                      \
    const unsigned short* hb = (HIN) + aoff;                                   \
    const bf16x8 A0 = *(const bf16x8*)(hb);                                    \
    const bf16x8 A1 = *(const bf16x8*)(hb + 32);                               \
    const bf16x8 A2 = *(const bf16x8*)(hb + 64);                               \
    const bf16x8 A3 = *(const bf16x8*)(hb + 96);                               \
    /* next step's P prefetch: broadcast offs read + 4 loads, off-path */      \
    {                                                                          \
      const float* Pn =                                                        \
          (const float*)(PjB + offs[((T) + 1) & (SEQ - 1)][row]);              \
      PB0 = Pn[0]; PB1 = Pn[128]; PB2 = Pn[256]; PB3 = Pn[384];                \
    }                                                                          \
    f32x4 a0 = {}, a1 = {}, a2 = {}, a3 = {};                                  \
    a0 = __builtin_amdgcn_mfma_f32_16x16x32_bf16(A0, Bfrag[0][0], a0, 0,0,0);  \
    a1 = __builtin_amdgcn_mfma_f32_16x16x32_bf16(A0, Bfrag[1][0], a1, 0,0,0);  \
    a2 = __builtin_amdgcn_mfma_f32_16x16x32_bf16(A0, Bfrag[2][0], a2, 0,0,0);  \
    a3 = __builtin_amdgcn_mfma_f32_16x16x32_bf16(A0, Bfrag[3][0], a3, 0,0,0);  \
    a0 = __builtin_amdgcn_mfma_f32_16x16x32_bf16(A1, Bfrag[0][1], a0, 0,0,0);  \
    a1 = __builtin_amdgcn_mfma_f32_16x16x32_bf16(A1, Bfrag[1][1], a1, 0,0,0);  \
    a2 = __builtin_amdgcn_mfma_f32_16x16x32_bf16(A1, Bfrag[2][1], a2, 0,0,0);  \
    a3 = __builtin_amdgcn_mfma_f32_16x16x32_bf16(A1, Bfrag[3][1], a3, 0,0,0);  \
    a0 = __builtin_amdgcn_mfma_f32_16x16x32_bf16(A2, Bfrag[0][2], a0, 0,0,0);  \
    a1 = __builtin_amdgcn_mfma_f32_16x16x32_bf16(A2, Bfrag[1][2], a1, 0,0,0);  \
    a2 = __builtin_amdgcn_mfma_f32_16x16x32_bf16(A2, Bfrag[2][2], a2, 0,0,0);  \
    a3 = __builtin_amdgcn_mfma_f32_16x16x32_bf16(A2, Bfrag[3][2], a3, 0,0,0);  \
    a0 = __builtin_amdgcn_mfma_f32_16x16x32_bf16(A3, Bfrag[0][3], a0, 0,0,0);  \
    a1 = __builtin_amdgcn_mfma_f32_16x16x32_bf16(A3, Bfrag[1][3], a1, 0,0,0);  \
    a2 = __builtin_amdgcn_mfma_f32_16x16x32_bf16(A3, Bfrag[2][3], a2, 0,0,0);  \
    a3 = __builtin_amdgcn_mfma_f32_16x16x32_bf16(A3, Bfrag[3][3], a3, 0,0,0);  \
    /* D row 4*kg (reg 0) = gates of batch row kg: no selects */               \
    const float iv = __builtin_amdgcn_rcpf(1.f + GEXP(-(a0[0] + PA0)));        \
    const float fv = __builtin_amdgcn_rcpf(1.f + GEXP(-(a1[0] + PA1)));        \
    const float gv = 1.f - 2.f * __builtin_amdgcn_rcpf(GEXP(a2[0] + PA2) + 1.f); \
    const float ov = __builtin_amdgcn_rcpf(1.f + GEXP(-(a3[0] + PA3)));        \
    cstate = fv * cstate + iv * gv;                                            \
    const float th =                                                           \
        1.f - 2.f * __builtin_amdgcn_rcpf(GEXP(cstate * SCALE_G) + 1.f);       \
    hv = ov * th;                                                              \
    unsigned int hpk;                                                          \
    asm("v_cvt_pk_bf16_f32 %0, %1, %2" : "=v"(hpk) : "v"(hv), "v"(hv));        \
    (HOUT)[row * HSTRIDE + jfull] = (unsigned short)hpk;                       \
    FAST_BARRIER();                                                            \
  }

  #pragma unroll 1
  for (int t = 0; t < SEQ; t += 2) {
    STEP(hbufA, hbufB, t,     p0, p1, p2, p3, q0, q1, q2, q3)
    STEP(hbufB, hbufA, t + 1, q0, q1, q2, q3, p0, p1, p2, p3)
  }
#undef STEP

  // final h written once
  h_last[row][jfull] = hv;
  __syncthreads();

  // classifier: 4 rows x 256 vocab = 1024 outputs, 2 per thread
  const int erow = tid >> 7;          // 0..3
  const int ej   = tid & 127;
  #pragma unroll
  for (int half = 0; half < 2; ++half) {
    const int v = ej + half * 128;
    float acc = b_cls[v];
    const float4* w  = (const float4*)(W_cls + v * HID);
    const float4* hh = (const float4*)&h_last[erow][0];
    #pragma unroll
    for (int k = 0; k < HID / 4; ++k) {
      const float4 wv = w[k];
      const float4 hv4 = hh[k];
      acc += wv.x * hv4.x + wv.y * hv4.y + wv.z * hv4.z + wv.w * hv4.w;
    }
    out[(b0 + erow) * VOCAB + v] = acc;
  }
}

extern "C" void kernel_launch(void* const* d_in, const int* in_sizes, int n_in,
                              void* d_out, int out_size, void* d_ws, size_t ws_size,
                              hipStream_t stream) {
  const int*   inputs = (const int*)d_in[0];
  const float* emb    = (const float*)d_in[1];
  const float* W_ih   = (const float*)d_in[2];
  const float* W_hh   = (const float*)d_in[3];
  const float* b_ih   = (const float*)d_in[4];
  const float* b_hh   = (const float*)d_in[5];
  const float* W_cls  = (const float*)d_in[6];
  const float* b_cls  = (const float*)d_in[7];
  float* outp = (float*)d_out;

  float* Ptab = (float*)d_ws;

  prep_kernel<<<VOCAB, 256, 0, stream>>>(emb, W_ih, b_ih, b_hh, Ptab);
  lstm_kernel<<<BATCH / 4, 512, 0, stream>>>(inputs, Ptab, W_hh, W_cls, b_cls, outp);
}

// Round 12
// 298.382 us; speedup vs baseline: 1.0563x; 1.0384x over previous
//
#include <hip/hip_runtime.h>
#include <hip/hip_bf16.h>

#define VOCAB 256
#define EMB   32
#define HID   128
#define GATES 512
#define BATCH 512
#define SEQ   512
#define HSTRIDE 144   // shorts; 288 B row stride -> conflict-light LDS access

#define LOG2E 1.442695041f
#if __has_builtin(__builtin_amdgcn_exp2f)
#define GEXP(x) __builtin_amdgcn_exp2f(x)
#define SCALE_IFO LOG2E
#define SCALE_G   (2.0f * LOG2E)
#else
#define GEXP(x) __expf(x)
#define SCALE_IFO 1.0f
#define SCALE_G   2.0f
#endif

// h-writes drained (lgkm), P global loads stay in flight across the barrier
#define FAST_BARRIER() asm volatile("s_waitcnt lgkmcnt(0)\n\ts_barrier" ::: "memory")

typedef __attribute__((ext_vector_type(8))) short bf16x8;
typedef __attribute__((ext_vector_type(4))) float f32x4;

static __device__ __forceinline__ unsigned short f2bf(float f) {
  unsigned int u = __float_as_uint(f);
  return (unsigned short)((u + 0x7fffu + ((u >> 16) & 1u)) >> 16);
}

// ws layout: P[VOCAB][GATES] f32 (512 KB), PRESCALED per gate type
// (i,f,o by SCALE_IFO; g by SCALE_G) so gate math uses raw 2^x.
__global__ __launch_bounds__(256) void prep_kernel(
    const float* __restrict__ emb, const float* __restrict__ W_ih,
    const float* __restrict__ b_ih, const float* __restrict__ b_hh,
    float* __restrict__ P) {
  const int wg  = blockIdx.x;
  const int tid = threadIdx.x;
  __shared__ float e[EMB];
  if (tid < EMB) e[tid] = emb[wg * EMB + tid];
  __syncthreads();
  for (int g = tid; g < GATES; g += 256) {
    float acc = b_ih[g] + b_hh[g];
    const float* w = W_ih + g * EMB;
    #pragma unroll
    for (int k = 0; k < EMB; ++k) acc += e[k] * w[k];
    const float sc = ((g >> 7) == 2) ? SCALE_G : SCALE_IFO;
    P[wg * GATES + g] = acc * sc;
  }
}

// 256 WGs x 256 threads (4 waves = 1/SIMD, ALL 256 CUs active).
// WG owns batch rows {2wg, 2wg+1}. Wave w owns j in [32w,32w+32) for all 4
// gate types: 8 n-tiles u = gt*2+jh (jh = j-half), 4 k-steps -> 32 MFMA/wave.
// A row m = h[m>>3] => D reg r at lane (c16,kg) = batch row kg>>1 (all regs
// identical); lane owns output (row=kg>>1, j=32w+16*(kg&1)+c16) [bijective].
// Gate gt = reg 0 of acc[2gt + (kg&1)]: one cndmask per gate.
// Rationale vs r11 (512thr/2 waves/SIMD): per-SIMD MFMA is invariant (32),
// but per-SIMD VALU halves (1 output/lane, one wave) and all CUs activate;
// barrier-locked waves never overlapped pipes anyway (r11 counters).
__global__ __launch_bounds__(256, 1) void lstm_kernel(
    const int* __restrict__ inputs, const float* __restrict__ P,
    const float* __restrict__ W_hh,
    const float* __restrict__ W_cls, const float* __restrict__ b_cls,
    float* __restrict__ out) {
  const int wg   = blockIdx.x;
  const int tid  = threadIdx.x;
  const int wave = tid >> 6;          // 0..3
  const int lane = tid & 63;
  const int c16  = lane & 15;
  const int kg   = lane >> 4;         // 0..3
  const int b0   = wg * 2;

  const int row   = kg >> 1;                       // batch row (0..1)
  const int jh    = kg & 1;                        // j-half in wave block
  const int jfull = wave * 32 + jh * 16 + c16;     // 0..127

  __shared__ unsigned int   offs[SEQ][2];         // 4 KB: P byte offsets
  __shared__ unsigned short hbufA[2 * HSTRIDE];
  __shared__ unsigned short hbufB[2 * HSTRIDE];
  __shared__ float          h_last[2][HID];       // 1 KB

  for (int k = tid; k < 2 * SEQ; k += 256) {
    const int r = k & 1, t = k >> 1;
    offs[t][r] = ((unsigned int)(inputs[(b0 + r) * SEQ + t] & 0xff)) << 11;
  }
  for (int k = tid; k < 2 * HSTRIDE; k += 256) { hbufA[k] = 0; hbufB[k] = 0; }

  // B-frags: W_hh f32 -> prescaled bf16 in-register (one-time; L2/L3-served)
  // Bfrag[u][ks] lane (c16,kg) = W_hh[gt*128+32w+16*(u&1)+c16][ks*32+kg*8..+7]
  bf16x8 Bfrag[8][4];
  #pragma unroll
  for (int u = 0; u < 8; ++u) {
    const int gt = u >> 1;
    const float sc = (gt == 2) ? SCALE_G : SCALE_IFO;
    const float* wr =
        W_hh + (gt * 128 + wave * 32 + (u & 1) * 16 + c16) * HID + kg * 8;
    #pragma unroll
    for (int ks = 0; ks < 4; ++ks) {
      const float4 w0 = *(const float4*)(wr + ks * 32);
      const float4 w1 = *(const float4*)(wr + ks * 32 + 4);
      bf16x8 b;
      b[0] = (short)f2bf(w0.x * sc); b[1] = (short)f2bf(w0.y * sc);
      b[2] = (short)f2bf(w0.z * sc); b[3] = (short)f2bf(w0.w * sc);
      b[4] = (short)f2bf(w1.x * sc); b[5] = (short)f2bf(w1.y * sc);
      b[6] = (short)f2bf(w1.z * sc); b[7] = (short)f2bf(w1.w * sc);
      Bfrag[u][ks] = b;
    }
  }

  // A-frag: lane (c16,kg) reads h[c16>>3][kg*8 .. +7] (+ks*32)
  const int aoff = (c16 >> 3) * HSTRIDE + kg * 8;
  const char* PjB = (const char*)(P + jfull);
  const f32x4 ZERO = {};               // shared C-in for first MFMA of each chain
  float cstate = 0.f;
  float hv = 0.f;

  __syncthreads();

  float p0, p1, p2, p3, q0, q1, q2, q3;
  {
    const float* Pr0 = (const float*)(PjB + offs[0][row]);
    p0 = Pr0[0]; p1 = Pr0[128]; p2 = Pr0[256]; p3 = Pr0[384];
  }

#define MFMA8(AK, KS, CIN0, CIN1, CIN2, CIN3, CIN4, CIN5, CIN6, CIN7)          \
    a0 = __builtin_amdgcn_mfma_f32_16x16x32_bf16(AK, Bfrag[0][KS], CIN0, 0,0,0); \
    a1 = __builtin_amdgcn_mfma_f32_16x16x32_bf16(AK, Bfrag[1][KS], CIN1, 0,0,0); \
    a2 = __builtin_amdgcn_mfma_f32_16x16x32_bf16(AK, Bfrag[2][KS], CIN2, 0,0,0); \
    a3 = __builtin_amdgcn_mfma_f32_16x16x32_bf16(AK, Bfrag[3][KS], CIN3, 0,0,0); \
    a4 = __builtin_amdgcn_mfma_f32_16x16x32_bf16(AK, Bfrag[4][KS], CIN4, 0,0,0); \
    a5 = __builtin_amdgcn_mfma_f32_16x16x32_bf16(AK, Bfrag[5][KS], CIN5, 0,0,0); \
    a6 = __builtin_amdgcn_mfma_f32_16x16x32_bf16(AK, Bfrag[6][KS], CIN6, 0,0,0); \
    a7 = __builtin_amdgcn_mfma_f32_16x16x32_bf16(AK, Bfrag[7][KS], CIN7, 0,0,0);

#define STEP(HIN, HOUT, T, PA0, PA1, PA2, PA3, PB0, PB1, PB2, PB3)             \
  {                                                                            \
    /* A-frag ds_reads FIRST: they gate the MFMA chain */                      \
    const unsigned short* hb = (HIN) + aoff;                                   \
    const bf16x8 A0 = *(const bf16x8*)(hb);                                    \
    const bf16x8 A1 = *(const bf16x8*)(hb + 32);                               \
    const bf16x8 A2 = *(const bf16x8*)(hb + 64);                               \
    const bf16x8 A3 = *(const bf16x8*)(hb + 96);                               \
    /* next step's P prefetch: broadcast offs read + 4 loads, off-path */      \
    {                                                                          \
      const float* Pn =                                                        \
          (const float*)(PjB + offs[((T) + 1) & (SEQ - 1)][row]);              \
      PB0 = Pn[0]; PB1 = Pn[128]; PB2 = Pn[256]; PB3 = Pn[384];                \
    }                                                                          \
    f32x4 a0, a1, a2, a3, a4, a5, a6, a7;                                      \
    MFMA8(A0, 0, ZERO, ZERO, ZERO, ZERO, ZERO, ZERO, ZERO, ZERO)               \
    MFMA8(A1, 1, a0, a1, a2, a3, a4, a5, a6, a7)                               \
    MFMA8(A2, 2, a0, a1, a2, a3, a4, a5, a6, a7)                               \
    MFMA8(A3, 3, a0, a1, a2, a3, a4, a5, a6, a7)                               \
    /* gate gt = reg 0 of acc[2gt + jh]: one cndmask per gate */               \
    const float gi = jh ? a1[0] : a0[0];                                       \
    const float gf = jh ? a3[0] : a2[0];                                       \
    const float gg = jh ? a5[0] : a4[0];                                       \
    const float go = jh ? a7[0] : a6[0];                                       \
    const float iv = __builtin_amdgcn_rcpf(1.f + GEXP(-(gi + PA0)));           \
    const float fv = __builtin_amdgcn_rcpf(1.f + GEXP(-(gf + PA1)));           \
    const float gv = 1.f - 2.f * __builtin_amdgcn_rcpf(GEXP(gg + PA2) + 1.f);  \
    const float ov = __builtin_amdgcn_rcpf(1.f + GEXP(-(go + PA3)));           \
    cstate = fv * cstate + iv * gv;                                            \
    const float th =                                                           \
        1.f - 2.f * __builtin_amdgcn_rcpf(GEXP(cstate * SCALE_G) + 1.f);       \
    hv = ov * th;                                                              \
    unsigned int hpk;                                                          \
    asm("v_cvt_pk_bf16_f32 %0, %1, %2" : "=v"(hpk) : "v"(hv), "v"(hv));        \
    (HOUT)[row * HSTRIDE + jfull] = (unsigned short)hpk;                       \
    FAST_BARRIER();                                                            \
  }

  #pragma unroll 1
  for (int t = 0; t < SEQ; t += 2) {
    STEP(hbufA, hbufB, t,     p0, p1, p2, p3, q0, q1, q2, q3)
    STEP(hbufB, hbufA, t + 1, q0, q1, q2, q3, p0, p1, p2, p3)
  }
#undef STEP
#undef MFMA8

  // final h written once
  h_last[row][jfull] = hv;
  __syncthreads();

  // classifier: 2 rows x 256 vocab = 512 outputs, 2 per thread
  const int erow = tid >> 7;          // 0..1
  const int ej   = tid & 127;
  #pragma unroll
  for (int half = 0; half < 2; ++half) {
    const int v = ej + half * 128;
    float acc = b_cls[v];
    const float4* w  = (const float4*)(W_cls + v * HID);
    const float4* hh = (const float4*)&h_last[erow][0];
    #pragma unroll
    for (int k = 0; k < HID / 4; ++k) {
      const float4 wv = w[k];
      const float4 hv4 = hh[k];
      acc += wv.x * hv4.x + wv.y * hv4.y + wv.z * hv4.z + wv.w * hv4.w;
    }
    out[(b0 + erow) * VOCAB + v] = acc;
  }
}

extern "C" void kernel_launch(void* const* d_in, const int* in_sizes, int n_in,
                              void* d_out, int out_size, void* d_ws, size_t ws_size,
                              hipStream_t stream) {
  const int*   inputs = (const int*)d_in[0];
  const float* emb    = (const float*)d_in[1];
  const float* W_ih   = (const float*)d_in[2];
  const float* W_hh   = (const float*)d_in[3];
  const float* b_ih   = (const float*)d_in[4];
  const float* b_hh   = (const float*)d_in[5];
  const float* W_cls  = (const float*)d_in[6];
  const float* b_cls  = (const float*)d_in[7];
  float* outp = (float*)d_out;

  float* Ptab = (float*)d_ws;

  prep_kernel<<<VOCAB, 256, 0, stream>>>(emb, W_ih, b_ih, b_hh, Ptab);
  lstm_kernel<<<BATCH / 2, 256, 0, stream>>>(inputs, Ptab, W_hh, W_cls, b_cls, outp);
}